// Round 1
// baseline (17492.793 us; speedup 1.0000x reference)
//
#include <hip/hip_runtime.h>
#include <hip/hip_bf16.h>
#include <math.h>

#define NB 32
#define NKS 2048
#define NKG 512
#define NH 512
#define NH3 1536
#define NV 32000
#define NSTEPS 64

typedef unsigned long long u64;
typedef unsigned int u32;
typedef unsigned short u16;

__device__ __forceinline__ float bfu(u32 u){ return __uint_as_float(u << 16); }

// monotone pack: larger float -> larger u64; equal float -> smaller index wins
__device__ __forceinline__ u64 packv(float v, int idx){
  u32 u = __float_as_uint(v);
  u = (u & 0x80000000u) ? ~u : (u | 0x80000000u);
  return (((u64)u) << 32) | (u32)(~(u32)idx);
}

// ---------------- one-time: fp32 -> bf16 (RNE) copies of both encoders -------
__global__ void k_cast(const float* __restrict__ sent, const float* __restrict__ graph,
                       u16* __restrict__ dsts, u16* __restrict__ dstg){
  const long NSg = (long)NB*NKS*NH/8;
  const long NGg = (long)NB*NKG*NH/8;
  long stride = (long)gridDim.x*blockDim.x;
  for (long g = (long)blockIdx.x*blockDim.x + threadIdx.x; g < NSg+NGg; g += stride){
    const float* src; u16* dst; long gg;
    if (g < NSg){ src = sent; dst = dsts; gg = g; } else { src = graph; dst = dstg; gg = g - NSg; }
    const float4* s4 = (const float4*)src + gg*2;
    float4 a = s4[0], b = s4[1];
    float vals[8] = {a.x,a.y,a.z,a.w,b.x,b.y,b.z,b.w};
    u16 o[8];
    #pragma unroll
    for (int i=0;i<8;i++){
      u32 bits = __float_as_uint(vals[i]);
      o[i] = (u16)((bits + 0x7FFFu + ((bits>>16)&1u)) >> 16);
    }
    uint4 out;
    out.x = (u32)o[0] | ((u32)o[1]<<16);
    out.y = (u32)o[2] | ((u32)o[3]<<16);
    out.z = (u32)o[4] | ((u32)o[5]<<16);
    out.w = (u32)o[6] | ((u32)o[7]<<16);
    *((uint4*)dst + gg) = out;
  }
}

__global__ void k_init(const float* __restrict__ enc, float* __restrict__ h){
  int i = blockIdx.x*256 + threadIdx.x;   // grid 64x256 == NB*NH
  h[i] = enc[i];
}

// ---------------- per step: q = W_a@h, gx = W_ih@emb[inp]+b, gh = W_hh@h+b ----
__global__ __launch_bounds__(512) void k_gates(
    const float* __restrict__ h, const float* __restrict__ Wa,
    const float* __restrict__ Wih, const float* __restrict__ Whh,
    const float* __restrict__ bih, const float* __restrict__ bhh,
    const float* __restrict__ emb, u64* __restrict__ packed,
    float* __restrict__ q, float* __restrict__ gx, float* __restrict__ gh, int step)
{
  __shared__ float4 xs4[NB*128];           // 64 KB: x-vectors for all 32 b
  int tid = threadIdx.x;
  int obase = blockIdx.x*64;               // 56 blocks x 64 outputs
  int typ = (obase < NH) ? 0 : (obase < NH+NH3 ? 1 : 2);
  const u64* prev = packed + ((step+1)&1)*NB;
  if (typ != 1){
    for (int i=tid;i<NB*128;i+=512) xs4[i] = ((const float4*)h)[i];
  } else {
    for (int i=tid;i<NB*128;i+=512){
      int b = i>>7;
      int inp = (step==0) ? 1 : (int)(~(u32)prev[b]);
      xs4[i] = ((const float4*)(emb + (size_t)inp*NH))[i&127];
    }
  }
  if (blockIdx.x==0 && tid<NB) packed[(size_t)(step&1)*NB + tid] = 0ULL; // reset cur slot
  __syncthreads();
  int lane = tid&63, bg = tid>>6;          // 8 b-groups x 4 b
  int o = obase + lane;
  const float* wrow; float bias; float* dst; int dstride, dcol;
  if (typ==0){ wrow = Wa + (size_t)o*NH; bias=0.f; dst=q; dstride=NH; dcol=o; }
  else if (typ==1){ int oo=o-NH; wrow = Wih + (size_t)oo*NH; bias=bih[oo]; dst=gx; dstride=NH3; dcol=oo; }
  else { int oo=o-NH-NH3; wrow = Whh + (size_t)oo*NH; bias=bhh[oo]; dst=gh; dstride=NH3; dcol=oo; }
  const float4* w4 = (const float4*)wrow;
  float acc[4] = {0.f,0.f,0.f,0.f};
  for (int k4=0;k4<128;k4++){
    float4 w = w4[k4];
    #pragma unroll
    for (int j=0;j<4;j++){
      float4 xv = xs4[(bg*4+j)*128 + k4];
      acc[j] += w.x*xv.x; acc[j] += w.y*xv.y; acc[j] += w.z*xv.z; acc[j] += w.w*xv.w;
    }
  }
  #pragma unroll
  for (int j=0;j<4;j++){
    int b = bg*4+j;
    dst[(size_t)b*dstride + dcol] = acc[j] + bias;
  }
}

// ---------------- per step: approximate scores + per-tile max ----------------
template<int BF>
__global__ __launch_bounds__(256) void k_scores(
   const u16* __restrict__ sh, const u16* __restrict__ g16,
   const float* __restrict__ sf, const float* __restrict__ gf,
   const float* __restrict__ q,
   float* __restrict__ ss, float* __restrict__ sg,
   float* __restrict__ tms, float* __restrict__ tmg)
{
  int blk = blockIdx.x, tid = threadIdx.x;
  int b, tile, K, nt; const u16* srch; const float* srcf; float* sc; float* tm;
  if (blk < 256){ b = blk>>3; tile = blk&7; K = NKS; srch = sh;  srcf = sf; sc = ss; tm = tms; nt=8; }
  else { int bb = blk-256; b = bb>>1; tile = bb&1; K = NKG; srch = g16; srcf = gf; sc = sg; tm = tmg; nt=2; }
  __shared__ float qs[NH];
  for (int i=tid;i<NH;i+=256) qs[i] = q[b*NH+i];
  __syncthreads();
  int key = tile*256 + tid;
  float acc = 0.f;
  if (BF){
    const u16* row = srch + ((size_t)b*K + key)*NH;
    for (int hh=0; hh<NH; hh+=8){
      uint4 u = *(const uint4*)(row+hh);
      acc += bfu(u.x&0xffffu)*qs[hh+0];
      acc += bfu(u.x>>16)    *qs[hh+1];
      acc += bfu(u.y&0xffffu)*qs[hh+2];
      acc += bfu(u.y>>16)    *qs[hh+3];
      acc += bfu(u.z&0xffffu)*qs[hh+4];
      acc += bfu(u.z>>16)    *qs[hh+5];
      acc += bfu(u.w&0xffffu)*qs[hh+6];
      acc += bfu(u.w>>16)    *qs[hh+7];
    }
  } else {
    const float4* row4 = (const float4*)(srcf + ((size_t)b*K + key)*NH);
    for (int k4=0;k4<128;k4++){
      float4 v = row4[k4];
      acc += v.x*qs[k4*4+0]; acc += v.y*qs[k4*4+1]; acc += v.z*qs[k4*4+2]; acc += v.w*qs[k4*4+3];
    }
  }
  sc[(size_t)b*K + key] = acc;
  __shared__ float red[256];
  red[tid] = acc; __syncthreads();
  for (int s=128;s>0;s>>=1){ if (tid<s) red[tid] = fmaxf(red[tid], red[tid+s]); __syncthreads(); }
  if (tid==0) tm[b*nt + tile] = red[0];
}

// ------- per step: select keys > max-24, exact fp32 scores+weighted values ---
__global__ __launch_bounds__(256) void k_ct(
  const float* __restrict__ sf, const float* __restrict__ gf,
  const float* __restrict__ q,
  const float* __restrict__ ss, const float* __restrict__ sg,
  const float* __restrict__ tms, const float* __restrict__ tmg,
  float* __restrict__ pcs, float* __restrict__ pcg,
  float* __restrict__ pds, float* __restrict__ pdg)
{
  int blk = blockIdx.x, tid = threadIdx.x;
  int b, tile, K, nt; const float* src; const float* sc; const float* tm; float* pct; float* pden;
  if (blk < 256){ b=blk>>3; tile=blk&7; K=NKS; nt=8; src=sf; sc=ss; tm=tms; pct=pcs; pden=pds; }
  else { int bb=blk-256; b=bb>>1; tile=bb&1; K=NKG; nt=2; src=gf; sc=sg; tm=tmg; pct=pcg; pden=pdg; }
  __shared__ float qs[NH];
  for (int i=tid;i<NH;i+=256) qs[i] = q[b*NH+i];
  float m = -1e30f;
  for (int i=0;i<nt;i++) m = fmaxf(m, tm[b*nt+i]);
  __syncthreads();
  int key = tile*256 + tid;
  float s = sc[(size_t)b*K + key];
  bool selp = (s > m - 24.0f);
  u64 mb = __ballot(selp);
  int lane = tid&63, wv = tid>>6;
  __shared__ int wcnt[4]; __shared__ int wbase[5];
  if (lane==0) wcnt[wv] = __popcll(mb);
  __syncthreads();
  if (tid==0){ int r=0; for (int w=0;w<4;w++){ wbase[w]=r; r+=wcnt[w]; } wbase[4]=r; }
  __syncthreads();
  int n = wbase[4];
  __shared__ int sel[256]; __shared__ float wexp[256];
  if (selp){
    int pos = wbase[wv] + __popcll(mb & ((1ULL<<lane)-1ULL));  // deterministic compaction
    sel[pos] = key;
  }
  __syncthreads();
  // exact fp32 scores for survivors: one wave per key
  for (int i=wv; i<n; i+=4){
    const float* vr = src + ((size_t)b*K + sel[i])*NH;
    const float4* vr4 = (const float4*)vr + lane*2;
    float4 p0 = vr4[0], p1 = vr4[1];
    int hb = lane*8;
    float a = p0.x*qs[hb+0]+p0.y*qs[hb+1]+p0.z*qs[hb+2]+p0.w*qs[hb+3]
            + p1.x*qs[hb+4]+p1.y*qs[hb+5]+p1.z*qs[hb+6]+p1.w*qs[hb+7];
    #pragma unroll
    for (int off=32; off>=1; off>>=1) a += __shfl_xor(a, off);
    if (lane==0) wexp[i] = expf(a - m);   // common reference m per (b,encoder): cancels in ratio
  }
  __syncthreads();
  float den = 0.f;
  for (int i=0;i<n;i++) den += wexp[i];
  float c0=0.f, c1=0.f; int h0 = tid*2;
  for (int i=0;i<n;i++){
    float w = wexp[i];
    const float2 vv = *(const float2*)(src + ((size_t)b*K + sel[i])*NH + h0);
    c0 += w*vv.x; c1 += w*vv.y;
  }
  float* pout = pct + ((size_t)(b*nt + tile))*NH;
  pout[h0] = c0; pout[h0+1] = c1;
  if (tid==0) pden[b*nt+tile] = den;
}

// -------- per step: combine partials, GRU, build x = [h', ct_g, ct_s] --------
__global__ __launch_bounds__(256) void k_comb(
  const float* __restrict__ pcs, const float* __restrict__ pcg,
  const float* __restrict__ pds, const float* __restrict__ pdg,
  const float* __restrict__ gx, const float* __restrict__ gh,
  float* __restrict__ h, float* __restrict__ x)
{
  int b = blockIdx.x, tid = threadIdx.x;
  float dens = 0.f, deng = 0.f;
  for (int i=0;i<8;i++) dens += pds[b*8+i];
  for (int i=0;i<2;i++) deng += pdg[b*2+i];
  float invs = 1.f/dens, invg = 1.f/deng;
  for (int i=tid; i<NH; i+=256){
    float cs = 0.f; for (int t=0;t<8;t++) cs += pcs[((size_t)(b*8+t))*NH + i];
    float cg = 0.f; for (int t=0;t<2;t++) cg += pcg[((size_t)(b*2+t))*NH + i];
    cs *= invs; cg *= invg;
    float xr = gx[(size_t)b*NH3 + i],        hr = gh[(size_t)b*NH3 + i];
    float xz = gx[(size_t)b*NH3 + NH + i],   hz = gh[(size_t)b*NH3 + NH + i];
    float xn = gx[(size_t)b*NH3 + 2*NH + i], hn = gh[(size_t)b*NH3 + 2*NH + i];
    float r = 1.f/(1.f+expf(-(xr+hr)));
    float z = 1.f/(1.f+expf(-(xz+hz)));
    float nn = tanhf(xn + r*hn);
    float hold = h[(size_t)b*NH + i];
    float hnew = (1.f - z)*nn + z*hold;
    h[(size_t)b*NH + i] = hnew;
    x[(size_t)b*NH3 + i] = hnew;
    x[(size_t)b*NH3 + NH + i] = cg;
    x[(size_t)b*NH3 + 2*NH + i] = cs;
  }
}

// -------- per step: logits = x @ W_out^T + b_out; argmax via atomicMax -------
__global__ __launch_bounds__(256) void k_logits(
  const float* __restrict__ x, const float* __restrict__ Wout,
  const float* __restrict__ bout, float* __restrict__ dst,
  u64* __restrict__ packed, int step)
{
  __shared__ float4 xs4[NB*128];   // 64 KB; reused for smax after the loop
  int tid = threadIdx.x;
  int bg = tid>>6, lane = tid&63;
  int vbase = blockIdx.x*128;      // 250 blocks
  int v0 = vbase + lane, v1 = vbase + 64 + lane;
  float acc0[8] = {0.f,0.f,0.f,0.f,0.f,0.f,0.f,0.f};
  float acc1[8] = {0.f,0.f,0.f,0.f,0.f,0.f,0.f,0.f};
  for (int c=0;c<3;c++){
    int kb = c*NH;
    for (int i=tid;i<NB*128;i+=256){
      int b=i>>7, kk=i&127;
      xs4[i] = ((const float4*)(x + (size_t)b*NH3 + kb))[kk];
    }
    __syncthreads();
    const float4* w0 = (const float4*)(Wout + (size_t)v0*NH3 + kb);
    const float4* w1 = (const float4*)(Wout + (size_t)v1*NH3 + kb);
    for (int k4=0;k4<128;k4++){
      float4 a = w0[k4], bb = w1[k4];
      #pragma unroll
      for (int j=0;j<8;j++){
        float4 xv = xs4[(bg*8+j)*128 + k4];
        acc0[j] += a.x*xv.x;  acc0[j] += a.y*xv.y;  acc0[j] += a.z*xv.z;  acc0[j] += a.w*xv.w;
        acc1[j] += bb.x*xv.x; acc1[j] += bb.y*xv.y; acc1[j] += bb.z*xv.z; acc1[j] += bb.w*xv.w;
      }
    }
    __syncthreads();
  }
  u64* smax = (u64*)xs4;
  if (tid<NB) smax[tid] = 0ULL;
  __syncthreads();
  float b0 = bout[v0], b1 = bout[v1];
  u64* cur = packed + (size_t)(step&1)*NB;
  #pragma unroll
  for (int j=0;j<8;j++){
    int b = bg*8+j;
    float r0 = acc0[j]+b0, r1 = acc1[j]+b1;
    dst[(size_t)b*NV + v0] = r0;
    dst[(size_t)b*NV + v1] = r1;
    u64 p0 = packv(r0, v0), p1 = packv(r1, v1);
    atomicMax(&smax[b], p0>p1?p0:p1);
  }
  __syncthreads();
  if (tid<NB) atomicMax(&cur[tid], smax[tid]);
}

extern "C" void kernel_launch(void* const* d_in, const int* in_sizes, int n_in,
                              void* d_out, int out_size, void* d_ws, size_t ws_size,
                              hipStream_t stream) {
  const float* sent  = (const float*)d_in[0];
  const float* graph = (const float*)d_in[1];
  const float* enc   = (const float*)d_in[2];
  const float* Wa    = (const float*)d_in[3];
  const float* emb   = (const float*)d_in[4];
  const float* Wih   = (const float*)d_in[5];
  const float* Whh   = (const float*)d_in[6];
  const float* bih   = (const float*)d_in[7];
  const float* bhh   = (const float*)d_in[8];
  const float* Wout  = (const float*)d_in[9];
  const float* bout  = (const float*)d_in[10];
  float* out = (float*)d_out;

  char* wsb = (char*)d_ws;
  size_t off = 0;
  auto alloc = [&](size_t nfloats)->float*{ float* p = (float*)(wsb + off); off += nfloats*4; return p; };
  float* h   = alloc(NB*NH);
  float* q   = alloc(NB*NH);
  float* gx  = alloc((size_t)NB*NH3);
  float* gh  = alloc((size_t)NB*NH3);
  float* ss  = alloc((size_t)NB*NKS);
  float* sg  = alloc((size_t)NB*NKG);
  float* tms = alloc(NB*8);
  float* tmg = alloc(NB*2);
  float* pcs = alloc((size_t)NB*8*NH);
  float* pcg = alloc((size_t)NB*2*NH);
  float* pds = alloc(NB*8);
  float* pdg = alloc(NB*2);
  float* x   = alloc((size_t)NB*NH3);
  u64* packed = (u64*)(wsb + off); off += 2*NB*8;
  size_t bfoff = (off + 255) & ~(size_t)255;
  size_t nS = (size_t)NB*NKS*NH, nG = (size_t)NB*NKG*NH;
  int usebf = (ws_size >= bfoff + (nS+nG)*2) ? 1 : 0;
  u16* sh16 = (u16*)(wsb + bfoff);
  u16* g16  = sh16 + nS;

  if (usebf) k_cast<<<dim3(4096), dim3(256), 0, stream>>>(sent, graph, sh16, g16);
  k_init<<<dim3(64), dim3(256), 0, stream>>>(enc, h);

  for (int t=0; t<NSTEPS; t++){
    k_gates<<<dim3(56), dim3(512), 0, stream>>>(h, Wa, Wih, Whh, bih, bhh, emb, packed, q, gx, gh, t);
    if (usebf)
      k_scores<1><<<dim3(320), dim3(256), 0, stream>>>(sh16, g16, sent, graph, q, ss, sg, tms, tmg);
    else
      k_scores<0><<<dim3(320), dim3(256), 0, stream>>>(sh16, g16, sent, graph, q, ss, sg, tms, tmg);
    k_ct<<<dim3(320), dim3(256), 0, stream>>>(sent, graph, q, ss, sg, tms, tmg, pcs, pcg, pds, pdg);
    k_comb<<<dim3(NB), dim3(256), 0, stream>>>(pcs, pcg, pds, pdg, gx, gh, h, x);
    k_logits<<<dim3(250), dim3(256), 0, stream>>>(x, Wout, bout, out + (size_t)t*NB*NV, packed, t);
  }
}